// Round 5
// baseline (144.008 us; speedup 1.0000x reference)
//
#include <hip/hip_runtime.h>
#include <math.h>

#define KK 32
#define CC 256

// ---------------------------------------------------------------------------
// Kernel 1: per-(b,m) stats, 256 blocks x 256 threads. Each block ALSO
// computes 2 rows of A from W1 (rows 2bm,2bm+1) — staged under x staging,
// verified bit-exact R2/R3/R4. All stats arithmetic byte-identical to R0
// (cov chain is knife-edge for the adj>0 mask).
// ---------------------------------------------------------------------------
__global__ __launch_bounds__(256) void prep_kernel(
    const float* __restrict__ x, const float* __restrict__ W1,
    float* __restrict__ mean_ws, float* __restrict__ A_ws,
    float* __restrict__ adj_out)
{
    __shared__ float xs[KK][258];
    __shared__ float rowlds[2][1056];
    __shared__ float part8[256];
    __shared__ float meanv[KK];
    __shared__ float covm[KK][KK + 1];
    __shared__ float stdv[KK];

    const int t  = threadIdx.x;
    const int bm = blockIdx.x;            // 0..255
    const int b  = bm >> 6, m = bm & 63;
    const float* xp = x + (size_t)bm * (KK * CC);

    {   // stage W1 rows 2bm, 2bm+1 (for A)
        const float* wr = W1 + (size_t)bm * 2048;
        #pragma unroll
        for (int u = 0; u < 2; ++u) {
            const int e4 = t + u * 256;
            const int q  = e4 >> 8;
            const int e  = (e4 & 255) * 4;
            const float4 v = *(const float4*)(wr + q * 1024 + e);
            const int f = (e >> 5) * 33 + (e & 31);
            rowlds[q][f] = v.x; rowlds[q][f + 1] = v.y;
            rowlds[q][f + 2] = v.z; rowlds[q][f + 3] = v.w;
        }
    }
    #pragma unroll
    for (int s = 0; s < 8; ++s) {
        const int e = s * 1024 + t * 4;
        const float4 v = *(const float4*)(xp + e);
        const int i = e >> 8, col = e & 255;
        xs[i][col] = v.x; xs[i][col + 1] = v.y;
        xs[i][col + 2] = v.z; xs[i][col + 3] = v.w;
    }
    __syncthreads();
    if (t < 64) {   // A rows: bit-identical reduction order (verified)
        const int k = t & 31, q = t >> 5;
        float rs = 0.f, cs = 0.f;
        #pragma unroll
        for (int j = 0; j < 32; ++j) rs += rowlds[q][k * 33 + j];
        #pragma unroll
        for (int i = 0; i < 32; ++i) cs += rowlds[q][i * 33 + k];
        A_ws[(size_t)(bm * 2 + q) * 32 + k] =
            0.5f * rs + cs - 0.5f * rowlds[q][k * 34];
    }
    {   // row-mean partials (identical tree to R0)
        const int i = t >> 3, part = t & 7;
        float s = 0.f;
        const int c0 = part * 32;
        #pragma unroll
        for (int c = 0; c < 32; ++c) s += xs[i][c0 + c];
        part8[t] = s;
    }
    __syncthreads();
    if (t < KK) {
        float s = 0.f;
        #pragma unroll
        for (int k = 0; k < 8; ++k) s += part8[t * 8 + k];
        meanv[t] = s * (1.0f / CC);
        mean_ws[(size_t)(b * 32 + t) * 64 + m] = meanv[t];
    }
    __syncthreads();
    {
        const int r = t >> 3, c0 = (t & 7) * 32;
        const float mv = meanv[r];
        #pragma unroll
        for (int c = 0; c < 32; ++c) xs[r][c0 + c] -= mv;
    }
    __syncthreads();
    if (t < 136) {
        int rem = t, r = 0;
        while (rem >= 16 - r) { rem -= 16 - r; ++r; }
        const int ti = r, tj = r + rem;
        const int i0 = 2 * ti, i1 = i0 + 1, j0 = 2 * tj, j1 = j0 + 1;
        float c00 = 0.f, c01 = 0.f, c10 = 0.f, c11 = 0.f;
        #pragma unroll 4
        for (int c = 0; c < CC; c += 2) {
            const float2 a0 = *(const float2*)&xs[i0][c];
            const float2 a1 = *(const float2*)&xs[i1][c];
            const float2 b0 = *(const float2*)&xs[j0][c];
            const float2 b1 = *(const float2*)&xs[j1][c];
            // sequential fma chain per accumulator — bit-exact
            c00 += a0.x * b0.x; c00 += a0.y * b0.y;
            c01 += a0.x * b1.x; c01 += a0.y * b1.y;
            c10 += a1.x * b0.x; c10 += a1.y * b0.y;
            c11 += a1.x * b1.x; c11 += a1.y * b1.y;
        }
        c00 *= (1.0f / (CC - 1)); c01 *= (1.0f / (CC - 1));
        c10 *= (1.0f / (CC - 1)); c11 *= (1.0f / (CC - 1));
        covm[i0][j0] = c00; covm[i0][j1] = c01;
        covm[i1][j0] = c10; covm[i1][j1] = c11;
        covm[j0][i0] = c00; covm[j1][i0] = c01;
        covm[j0][i1] = c10; covm[j1][i1] = c11;
    }
    __syncthreads();
    if (t < KK) stdv[t] = sqrtf(covm[t][t]);
    __syncthreads();
    #pragma unroll
    for (int k = 0; k < 4; ++k) {
        const int pair = t + k * 256;
        const int i = pair >> 5, j = pair & 31;
        adj_out[(size_t)bm * 1024 + pair] = covm[i][j] / (stdv[i] * stdv[j]);
    }
}

// ---------------------------------------------------------------------------
// Kernel 2 (NEW, fused h+e): e = sigmoid(W2 @ gelu(A @ mean)). Grid (64,4),
// block = 64 m x 4 ow. W2 tile [16][512] in LDS (verified staging). h is
// recomputed in-block, c-chunked (4 x 128):
//   h chain: k-ascending dot vs mean + identical gelu  -> same bits as
//            the verified h_kernel;
//   e chain: c-ascending across sequential chunks, x/y/z/w fmac order
//            within float4 -> same bits as the verified e_kernel.
// Removes one serial launch + the h_ws global round-trip; costs ~3 us of
// redundant (parallel) VALU.
// ---------------------------------------------------------------------------
__global__ __launch_bounds__(256) void he_kernel(
    const float* __restrict__ W2, const float* __restrict__ A_ws,
    const float* __restrict__ mean_ws, float* __restrict__ e_ws)
{
    __shared__ float W2s[16][512];     // 32 KB
    __shared__ float Ach[128][33];     // 16.9 KB (A rows of current c-chunk)
    __shared__ float hch[128][65];     // 33.3 KB (h[c][m] of current chunk)
    __shared__ float mvs[32][65];      //  8.3 KB (mean[k][m] for this b)

    const int m  = threadIdx.x;        // 0..63
    const int ow = threadIdx.y;        // 0..3
    const int t  = ow * 64 + m;
    const int b  = blockIdx.y;
    const int ob = blockIdx.x * 16;
    const int ol = ow * 4;

    {   // stage W2 tile — verified pattern
        const float* src = W2 + (size_t)ob * 512;
        #pragma unroll
        for (int u = 0; u < 8; ++u) {
            const int e4 = t + u * 256;
            const float4 v = *(const float4*)(src + e4 * 4);
            *(float4*)&W2s[e4 >> 7][(e4 & 127) * 4] = v;
        }
    }
    {   // stage mean[k][m] (2048 floats, coalesced)
        const float* src = mean_ws + (size_t)b * 2048;
        #pragma unroll
        for (int u = 0; u < 2; ++u) {
            const int e4 = t + u * 256;
            const float4 v = *(const float4*)(src + e4 * 4);
            const int k = e4 >> 4, m0 = (e4 & 15) * 4;
            mvs[k][m0] = v.x; mvs[k][m0 + 1] = v.y;
            mvs[k][m0 + 2] = v.z; mvs[k][m0 + 3] = v.w;
        }
    }
    __syncthreads();

    float mr[32];                      // this thread's mean column
    #pragma unroll
    for (int k = 0; k < 32; ++k) mr[k] = mvs[k][m];

    float acc[4] = {0.f, 0.f, 0.f, 0.f};

    for (int cc = 0; cc < 4; ++cc) {
        const int c0 = cc * 128;
        {   // stage A rows [c0, c0+128) — coalesced float4
            const float* src = A_ws + (size_t)c0 * 32;
            #pragma unroll
            for (int u = 0; u < 4; ++u) {
                const int e4 = t + u * 256;
                const float4 v = *(const float4*)(src + e4 * 4);
                const int row = e4 >> 3, k0 = (e4 & 7) * 4;
                Ach[row][k0]     = v.x; Ach[row][k0 + 1] = v.y;
                Ach[row][k0 + 2] = v.z; Ach[row][k0 + 3] = v.w;
            }
        }
        __syncthreads();
        {   // h chunk: 32 rows per wave (cl wave-uniform -> Ach broadcast)
            #pragma unroll 4
            for (int i = 0; i < 32; ++i) {
                const int cl = ow * 32 + i;
                float s = 0.f;
                #pragma unroll
                for (int k = 0; k < 32; ++k) s += Ach[cl][k] * mr[k]; // k-asc
                const float g =
                    0.5f * s * (1.0f + erff(s * 0.70710678118654752f));
                hch[cl][m] = g;
            }
        }
        __syncthreads();
        {   // e partial: identical c-ascending x/y/z/w chain
            #pragma unroll 4
            for (int cl = 0; cl < 128; cl += 4) {
                const int c = c0 + cl;
                const float hv0 = hch[cl + 0][m];
                const float hv1 = hch[cl + 1][m];
                const float hv2 = hch[cl + 2][m];
                const float hv3 = hch[cl + 3][m];
                #pragma unroll
                for (int q = 0; q < 4; ++q) {
                    const float4 w = *(const float4*)&W2s[ol + q][c];
                    acc[q] += w.x * hv0;
                    acc[q] += w.y * hv1;
                    acc[q] += w.z * hv2;
                    acc[q] += w.w * hv3;
                }
            }
        }
        __syncthreads();
    }

    float4 sv;
    sv.x = 1.0f / (1.0f + expf(-acc[0]));
    sv.y = 1.0f / (1.0f + expf(-acc[1]));
    sv.z = 1.0f / (1.0f + expf(-acc[2]));
    sv.w = 1.0f / (1.0f + expf(-acc[3]));
    *(float4*)&e_ws[(size_t)(b * 64 + m) * 1024 + ob + ol] = sv;
}

// ---------------------------------------------------------------------------
// Kernel 3: masked softmax + att @ x. Byte-identical to R0's version
// (part of the best 100.1 us measurement). 256 blocks (b,m).
// ---------------------------------------------------------------------------
__global__ __launch_bounds__(256) void softmax_out_kernel(
    const float* __restrict__ x, const float* __restrict__ e_ws,
    const float* __restrict__ adj, float* __restrict__ out)
{
    __shared__ float xs[KK][260];
    __shared__ float att[KK][KK + 1];
    const int bm = blockIdx.x;
    const int b  = bm >> 6, m = bm & 63;
    const int t  = threadIdx.x;
    const float* xp = x + (size_t)bm * (KK * CC);

    #pragma unroll
    for (int s = 0; s < 8; ++s) {
        const int e = s * 1024 + t * 4;
        const float4 v = *(const float4*)(xp + e);
        *(float4*)&xs[e >> 8][e & 255] = v;
    }
    {
        const int p0 = 4 * t;
        const float4 ev4 = *(const float4*)&e_ws[(size_t)(b * 64 + m) * 1024 + p0];
        const float4 aj4 = *(const float4*)&adj[(size_t)bm * 1024 + p0];
        const int i = p0 >> 5, j0 = p0 & 31;
        att[i][j0]     = (aj4.x > 0.f) ? ev4.x : -INFINITY;
        att[i][j0 + 1] = (aj4.y > 0.f) ? ev4.y : -INFINITY;
        att[i][j0 + 2] = (aj4.z > 0.f) ? ev4.z : -INFINITY;
        att[i][j0 + 3] = (aj4.w > 0.f) ? ev4.w : -INFINITY;
    }
    __syncthreads();
    if (t < KK) {
        float mx = -INFINITY;
        #pragma unroll
        for (int j = 0; j < KK; ++j) mx = fmaxf(mx, att[t][j]);
        float s = 0.f;
        #pragma unroll
        for (int j = 0; j < KK; ++j) {
            const float v = expf(att[t][j] - mx);
            att[t][j] = v;
            s += v;
        }
        const float inv = 1.0f / s;
        #pragma unroll
        for (int j = 0; j < KK; ++j) att[t][j] *= inv;
    }
    __syncthreads();

    const int c8 = t & 31, iq = t >> 5;
    const int i0 = iq * 4;
    const int cA = 4 * c8, cB = 128 + 4 * c8;
    float4 accA[4], accB[4];
    #pragma unroll
    for (int r = 0; r < 4; ++r) {
        accA[r] = make_float4(0.f, 0.f, 0.f, 0.f);
        accB[r] = make_float4(0.f, 0.f, 0.f, 0.f);
    }
    #pragma unroll 2
    for (int j = 0; j < KK; ++j) {
        const float4 xa = *(const float4*)&xs[j][cA];
        const float4 xb = *(const float4*)&xs[j][cB];
        #pragma unroll
        for (int r = 0; r < 4; ++r) {
            const float av = att[i0 + r][j];
            accA[r].x += av * xa.x; accA[r].y += av * xa.y;
            accA[r].z += av * xa.z; accA[r].w += av * xa.w;
            accB[r].x += av * xb.x; accB[r].y += av * xb.y;
            accB[r].z += av * xb.z; accB[r].w += av * xb.w;
        }
    }
    float* op = out + (size_t)bm * (KK * CC);
    #pragma unroll
    for (int r = 0; r < 4; ++r) {
        *(float4*)(op + (size_t)(i0 + r) * CC + cA) = accA[r];
        *(float4*)(op + (size_t)(i0 + r) * CC + cB) = accB[r];
    }
}

extern "C" void kernel_launch(void* const* d_in, const int* in_sizes, int n_in,
                              void* d_out, int out_size, void* d_ws, size_t ws_size,
                              hipStream_t stream) {
    const float* x  = (const float*)d_in[0];   // (4,64,32,256)
    const float* W1 = (const float*)d_in[1];   // (512,1024)
    const float* W2 = (const float*)d_in[2];   // (1024,512)
    float* out     = (float*)d_out;                       // 2,097,152 floats
    float* adj_out = out + (size_t)4 * 64 * 32 * 256;     // +262,144 floats

    float* mean_ws = (float*)d_ws;                    // 4*32*64 =   8,192
    float* A_ws    = mean_ws + 8192;                  // 512*32  =  16,384
    float* e_ws    = A_ws + 16384;                    // 4*64*1024 = 262,144

    prep_kernel<<<256, 256, 0, stream>>>(x, W1, mean_ws, A_ws, adj_out);
    he_kernel<<<dim3(64, 4), dim3(64, 4), 0, stream>>>(W2, A_ws, mean_ws, e_ws);
    softmax_out_kernel<<<256, 256, 0, stream>>>(x, e_ws, adj_out, out);
}

// Round 6
// 100.897 us; speedup vs baseline: 1.4273x; 1.4273x over previous
//
#include <hip/hip_runtime.h>
#include <math.h>

#define KK 32
#define CC 256

// ---------------------------------------------------------------------------
// Kernel 1: per-(b,m) stats. 256 blocks, 256 threads (pure — no A blocks).
// Stage x in LDS (stride 258), row means, center, cov upper-tri via 2x2
// register tiles (BIT-EXACT sequential fma chain — adj>0 mask is knife-edge),
// adj -> out region, means -> mean_ws.
// ---------------------------------------------------------------------------
__global__ __launch_bounds__(256) void prep_kernel(
    const float* __restrict__ x, float* __restrict__ mean_ws,
    float* __restrict__ adj_out)
{
    __shared__ float xs[KK][258];
    __shared__ float part8[256];
    __shared__ float meanv[KK];
    __shared__ float covm[KK][KK + 1];
    __shared__ float stdv[KK];

    const int t  = threadIdx.x;
    const int bm = blockIdx.x;            // 0..255
    const int b  = bm >> 6, m = bm & 63;
    const float* xp = x + (size_t)bm * (KK * CC);

    #pragma unroll
    for (int s = 0; s < 8; ++s) {
        const int e = s * 1024 + t * 4;
        const float4 v = *(const float4*)(xp + e);
        const int i = e >> 8, col = e & 255;
        xs[i][col] = v.x; xs[i][col + 1] = v.y;
        xs[i][col + 2] = v.z; xs[i][col + 3] = v.w;
    }
    __syncthreads();
    {
        const int i = t >> 3, part = t & 7;
        float s = 0.f;
        const int c0 = part * 32;
        #pragma unroll
        for (int c = 0; c < 32; ++c) s += xs[i][c0 + c];
        part8[t] = s;
    }
    __syncthreads();
    if (t < KK) {
        float s = 0.f;
        #pragma unroll
        for (int k = 0; k < 8; ++k) s += part8[t * 8 + k];
        meanv[t] = s * (1.0f / CC);
        mean_ws[(size_t)(b * 32 + t) * 64 + m] = meanv[t];
    }
    __syncthreads();
    {
        const int r = t >> 3, c0 = (t & 7) * 32;
        const float mv = meanv[r];
        #pragma unroll
        for (int c = 0; c < 32; ++c) xs[r][c0 + c] -= mv;
    }
    __syncthreads();
    if (t < 136) {
        int rem = t, r = 0;
        while (rem >= 16 - r) { rem -= 16 - r; ++r; }
        const int ti = r, tj = r + rem;
        const int i0 = 2 * ti, i1 = i0 + 1, j0 = 2 * tj, j1 = j0 + 1;
        float c00 = 0.f, c01 = 0.f, c10 = 0.f, c11 = 0.f;
        for (int c = 0; c < CC; c += 2) {
            const float2 a0 = *(const float2*)&xs[i0][c];
            const float2 a1 = *(const float2*)&xs[i1][c];
            const float2 b0 = *(const float2*)&xs[j0][c];
            const float2 b1 = *(const float2*)&xs[j1][c];
            // sequential fma chain per accumulator — bit-exact vs R3
            c00 += a0.x * b0.x; c00 += a0.y * b0.y;
            c01 += a0.x * b1.x; c01 += a0.y * b1.y;
            c10 += a1.x * b0.x; c10 += a1.y * b0.y;
            c11 += a1.x * b1.x; c11 += a1.y * b1.y;
        }
        c00 *= (1.0f / (CC - 1)); c01 *= (1.0f / (CC - 1));
        c10 *= (1.0f / (CC - 1)); c11 *= (1.0f / (CC - 1));
        covm[i0][j0] = c00; covm[i0][j1] = c01;
        covm[i1][j0] = c10; covm[i1][j1] = c11;
        covm[j0][i0] = c00; covm[j1][i0] = c01;
        covm[j0][i1] = c10; covm[j1][i1] = c11;
    }
    __syncthreads();
    if (t < KK) stdv[t] = sqrtf(covm[t][t]);
    __syncthreads();
    #pragma unroll
    for (int k = 0; k < 4; ++k) {
        const int pair = t + k * 256;
        const int i = pair >> 5, j = pair & 31;
        adj_out[(size_t)bm * 1024 + pair] = covm[i][j] / (stdv[i] * stdv[j]);
    }
}

// ---------------------------------------------------------------------------
// Kernel 2: A rows from W1 (bit-identical reduction order to R3's a_init:
// A[o,k] = 0.5f*rowsum_k + colsum_k - 0.5f*W1[o,33k]) computed in-block,
// then h = gelu(A @ mean). Block (og, b), 64 threads, 4 o's per block.
// ---------------------------------------------------------------------------
__global__ __launch_bounds__(64) void mlp1_kernel(
    const float* __restrict__ W1, const float* __restrict__ mean_ws,
    float* __restrict__ h_ws)
{
    __shared__ float rowlds[4][1056];   // element 32k+j of row q at [q][k*33+j]
    __shared__ float Al[4][32];
    const int t  = threadIdx.x;         // 0..63
    const int b  = blockIdx.y;
    const int ob = blockIdx.x * 4;

    const float* wr = W1 + (size_t)ob * 1024;
    #pragma unroll
    for (int u = 0; u < 16; ++u) {
        const int e4 = t + u * 64;          // float4 index over 4 rows
        const int q  = e4 >> 8;
        const int e  = (e4 & 255) * 4;
        const float4 v = *(const float4*)(wr + q * 1024 + e);
        const int f = (e >> 5) * 33 + (e & 31);
        rowlds[q][f] = v.x; rowlds[q][f + 1] = v.y;
        rowlds[q][f + 2] = v.z; rowlds[q][f + 3] = v.w;
    }
    __syncthreads();
    {
        const int k = t & 31, qh = t >> 5;
        #pragma unroll
        for (int qq = 0; qq < 2; ++qq) {
            const int q = qh + qq * 2;
            float rs = 0.f, cs = 0.f;
            #pragma unroll
            for (int j = 0; j < 32; ++j) rs += rowlds[q][k * 33 + j];
            #pragma unroll
            for (int i = 0; i < 32; ++i) cs += rowlds[q][i * 33 + k];
            Al[q][k] = 0.5f * rs + cs - 0.5f * rowlds[q][k * 34];
        }
    }
    __syncthreads();
    const int m = t;
    float mr[32];
    #pragma unroll
    for (int k = 0; k < 32; ++k) mr[k] = mean_ws[(size_t)(b * 32 + k) * 64 + m];
    #pragma unroll
    for (int q = 0; q < 4; ++q) {
        float a = 0.f;
        #pragma unroll
        for (int k = 0; k < 32; ++k) a += Al[q][k] * mr[k];   // k-ascending, bit-exact
        const float g = 0.5f * a * (1.0f + erff(a * 0.70710678118654752f));
        h_ws[(size_t)(b * 512 + ob + q) * 64 + m] = g;
    }
}

// ---------------------------------------------------------------------------
// Kernel 3: e = sigmoid(W2 @ h). Block = 16 o x 64 m (4 waves), grid (64,4).
// W2 tile in LDS, wave-uniform float4 broadcasts; h coalesced; acc chain
// c-ascending (bit-exact vs R3). e_ws layout [b][m][o], one float4
// store per thread (scattered stores instead of scattered softmax reads).
// ---------------------------------------------------------------------------
__global__ __launch_bounds__(256) void mlp2_kernel(
    const float* __restrict__ W2, const float* __restrict__ h_ws,
    float* __restrict__ e_ws)
{
    __shared__ float W2s[16][512];     // 32 KB
    const int m  = threadIdx.x;        // 0..63
    const int ow = threadIdx.y;        // 0..3
    const int b  = blockIdx.y;
    const int ob = blockIdx.x * 16;

    {
        const int t = ow * 64 + m;
        const float* src = W2 + (size_t)ob * 512;
        #pragma unroll
        for (int u = 0; u < 8; ++u) {
            const int e4 = t + u * 256;
            const float4 v = *(const float4*)(src + e4 * 4);
            *(float4*)&W2s[e4 >> 7][(e4 & 127) * 4] = v;
        }
    }
    __syncthreads();

    const float* hb = h_ws + (size_t)b * 512 * 64 + m;
    float acc[4] = {0.f, 0.f, 0.f, 0.f};
    const int ol = ow * 4;

    for (int c = 0; c < 512; c += 4) {
        const float hv0 = hb[(size_t)(c + 0) * 64];
        const float hv1 = hb[(size_t)(c + 1) * 64];
        const float hv2 = hb[(size_t)(c + 2) * 64];
        const float hv3 = hb[(size_t)(c + 3) * 64];
        #pragma unroll
        for (int q = 0; q < 4; ++q) {
            const float4 w = *(const float4*)&W2s[ol + q][c];  // broadcast
            acc[q] += w.x * hv0;
            acc[q] += w.y * hv1;
            acc[q] += w.z * hv2;
            acc[q] += w.w * hv3;
        }
    }
    float4 sv;
    sv.x = 1.0f / (1.0f + expf(-acc[0]));
    sv.y = 1.0f / (1.0f + expf(-acc[1]));
    sv.z = 1.0f / (1.0f + expf(-acc[2]));
    sv.w = 1.0f / (1.0f + expf(-acc[3]));
    *(float4*)&e_ws[(size_t)(b * 64 + m) * 1024 + ob + ol] = sv;
}

// ---------------------------------------------------------------------------
// Kernel 4: masked softmax (mask adj>0) + att @ x.  256 blocks (b,m).
// e and adj reads fully-coalesced float4 (e layout [b][m][o]).
// ---------------------------------------------------------------------------
__global__ __launch_bounds__(256) void softmax_out_kernel(
    const float* __restrict__ x, const float* __restrict__ e_ws,
    const float* __restrict__ adj, float* __restrict__ out)
{
    __shared__ float xs[KK][260];
    __shared__ float att[KK][KK + 1];
    const int bm = blockIdx.x;
    const int b  = bm >> 6, m = bm & 63;
    const int t  = threadIdx.x;
    const float* xp = x + (size_t)bm * (KK * CC);

    #pragma unroll
    for (int s = 0; s < 8; ++s) {
        const int e = s * 1024 + t * 4;
        const float4 v = *(const float4*)(xp + e);
        *(float4*)&xs[e >> 8][e & 255] = v;
    }
    {
        const int p0 = 4 * t;
        const float4 ev4 = *(const float4*)&e_ws[(size_t)(b * 64 + m) * 1024 + p0];
        const float4 aj4 = *(const float4*)&adj[(size_t)bm * 1024 + p0];
        const int i = p0 >> 5, j0 = p0 & 31;
        att[i][j0]     = (aj4.x > 0.f) ? ev4.x : -INFINITY;
        att[i][j0 + 1] = (aj4.y > 0.f) ? ev4.y : -INFINITY;
        att[i][j0 + 2] = (aj4.z > 0.f) ? ev4.z : -INFINITY;
        att[i][j0 + 3] = (aj4.w > 0.f) ? ev4.w : -INFINITY;
    }
    __syncthreads();
    if (t < KK) {
        float mx = -INFINITY;
        #pragma unroll
        for (int j = 0; j < KK; ++j) mx = fmaxf(mx, att[t][j]);
        float s = 0.f;
        #pragma unroll
        for (int j = 0; j < KK; ++j) {
            const float v = expf(att[t][j] - mx);
            att[t][j] = v;
            s += v;
        }
        const float inv = 1.0f / s;
        #pragma unroll
        for (int j = 0; j < KK; ++j) att[t][j] *= inv;
    }
    __syncthreads();

    const int c8 = t & 31, iq = t >> 5;
    const int i0 = iq * 4;
    const int cA = 4 * c8, cB = 128 + 4 * c8;
    float4 accA[4], accB[4];
    #pragma unroll
    for (int r = 0; r < 4; ++r) {
        accA[r] = make_float4(0.f, 0.f, 0.f, 0.f);
        accB[r] = make_float4(0.f, 0.f, 0.f, 0.f);
    }
    for (int j = 0; j < KK; ++j) {
        const float4 xa = *(const float4*)&xs[j][cA];
        const float4 xb = *(const float4*)&xs[j][cB];
        #pragma unroll
        for (int r = 0; r < 4; ++r) {
            const float av = att[i0 + r][j];
            accA[r].x += av * xa.x; accA[r].y += av * xa.y;
            accA[r].z += av * xa.z; accA[r].w += av * xa.w;
            accB[r].x += av * xb.x; accB[r].y += av * xb.y;
            accB[r].z += av * xb.z; accB[r].w += av * xb.w;
        }
    }
    float* op = out + (size_t)bm * (KK * CC);
    #pragma unroll
    for (int r = 0; r < 4; ++r) {
        *(float4*)(op + (size_t)(i0 + r) * CC + cA) = accA[r];
        *(float4*)(op + (size_t)(i0 + r) * CC + cB) = accB[r];
    }
}

extern "C" void kernel_launch(void* const* d_in, const int* in_sizes, int n_in,
                              void* d_out, int out_size, void* d_ws, size_t ws_size,
                              hipStream_t stream) {
    const float* x  = (const float*)d_in[0];   // (4,64,32,256)
    const float* W1 = (const float*)d_in[1];   // (512,1024)
    const float* W2 = (const float*)d_in[2];   // (1024,512)
    float* out     = (float*)d_out;                       // 2,097,152 floats
    float* adj_out = out + (size_t)4 * 64 * 32 * 256;     // +262,144 floats

    float* mean_ws = (float*)d_ws;                    // 4*32*64   =   8,192
    float* h_ws    = mean_ws + 8192;                  // 4*512*64  = 131,072
    float* e_ws    = h_ws + 131072;                   // 4*64*1024 = 262,144

    prep_kernel<<<256, 256, 0, stream>>>(x, mean_ws, adj_out);
    mlp1_kernel<<<dim3(128, 4), 64, 0, stream>>>(W1, mean_ws, h_ws);
    mlp2_kernel<<<dim3(64, 4), dim3(64, 4), 0, stream>>>(W2, h_ws, e_ws);
    softmax_out_kernel<<<256, 256, 0, stream>>>(x, e_ws, adj_out, out);
}